// Round 3
// baseline (122.893 us; speedup 1.0000x reference)
//
#include <hip/hip_runtime.h>
#include <cstddef>

#define EPS 1e-5f

constexpr int NG  = 8192;   // genes
constexpr int HID = 32768;  // hidden (= NG*4)
constexpr int NTF = 1024;   // TFs
constexpr int B   = 256;    // batch

// round-to-nearest-even f32 -> bf16 bits (no NaN inputs in this problem)
static __device__ __forceinline__ unsigned short f2bf(float v) {
    union { float f; unsigned u; } a; a.f = v;
    unsigned r = a.u + 0x7fffu + ((a.u >> 16) & 1u);
    return (unsigned short)(r >> 16);
}

// ---------------------------------------------------------------------------
// Kernel 1: fused  sparse-L1 -> relu -> BN1 -> sparse-L2(4x4 blockdiag) -> relu
// Single x pass (x in 32 VGPRs), 1024 blocks (4/CU).
// XCD swizzle: cb = ((bid&7)<<7)|(bid>>3) puts a contiguous 128-column
// (32-gene) range per XCD-slot so x cachelines are consumed within one XCD's
// L2 (unswizzled, line-sharing blocks land on 4 different XCDs = 4x fetch).
// Writes relu(h2) gene-contiguous: h2[c][r] bf16, gene = 2 KB contiguous.
// XCD x writes exactly gene slice [1024x,1024x+1024) = what gather3 reads.
// Emits per-column (mean2, invstd2) so BN2 folds into layer-3 weights.
// ---------------------------------------------------------------------------
__global__ __launch_bounds__(256) void fused12(
    const float* __restrict__ x,       // [B][NG]
    const float* __restrict__ w1,      // [HID]
    const float* __restrict__ b1,      // [HID]
    const float* __restrict__ w2,      // [HID*4]
    const float* __restrict__ b2,      // [HID]
    unsigned short* __restrict__ h2,   // [HID][B] bf16 bits
    float* __restrict__ m2g,           // [HID]
    float* __restrict__ inv2g)         // [HID]
{
    const int lane  = threadIdx.x & 31;   // column within 32-col tile
    const int slice = threadIdx.x >> 5;   // 8 slices x 32 rows
    const int cb    = ((blockIdx.x & 7) << 7) | (blockIdx.x >> 3);  // XCD swizzle
    const int c     = (cb << 5) + lane;   // global hidden column
    const int g     = c >> 2;             // gene
    const int r0    = slice << 5;         // first batch row of my slice

    __shared__ float redA[8][32], redB[8][32];
    __shared__ float m1s[32], inv1s[32];

    const float w1c = w1[c], b1c = b1[c];
    const float* xp = x + (size_t)r0 * NG + g;

    // ---- phase A: load x once into registers; BN1 stats for column c ----
    float xv[32];
    float s = 0.f, s2 = 0.f;
    #pragma unroll
    for (int i = 0; i < 32; ++i) {
        float v = xp[(size_t)i * NG];
        xv[i] = v;
        float h = fmaxf(fmaf(w1c, v, b1c), 0.f);
        s += h;
        s2 = fmaf(h, h, s2);
    }
    redA[slice][lane] = s;
    redB[slice][lane] = s2;
    __syncthreads();
    if (threadIdx.x < 32) {
        float S = 0.f, S2 = 0.f;
        #pragma unroll
        for (int k = 0; k < 8; ++k) { S += redA[k][threadIdx.x]; S2 += redB[k][threadIdx.x]; }
        float m = S * (1.f / 256.f);
        float v = fmaf(-m, m, S2 * (1.f / 256.f));
        m1s[threadIdx.x]   = m;
        inv1s[threadIdx.x] = rsqrtf(v + EPS);
    }
    __syncthreads();

    // ---- fold BN1 into the 4x4 block weights ----
    const int lbase = lane & ~3;   // first column of my gene in LDS tile
    const int gbase = g << 2;      // first global column of my gene
    float w1j[4], b1j[4], w2s[4];
    float bconst = b2[c];
    #pragma unroll
    for (int j = 0; j < 4; ++j) {
        w1j[j] = w1[gbase + j];
        b1j[j] = b1[gbase + j];
        float wv = w2[(c << 2) + j] * inv1s[lbase + j];
        w2s[j] = wv;
        bconst = fmaf(-wv, m1s[lbase + j], bconst);
    }

    // ---- phase B: recompute h1 from registers, folded L2, relu, BN2 stats ----
    float t2s = 0.f, t2s2 = 0.f;
    unsigned short* op = h2 + (size_t)c * B + r0;
    for (int i0 = 0; i0 < 32; i0 += 4) {
        ushort4 pk;
        unsigned short* pp = (unsigned short*)&pk;
        #pragma unroll
        for (int u = 0; u < 4; ++u) {
            float v = xv[i0 + u];
            float acc = bconst;
            #pragma unroll
            for (int j = 0; j < 4; ++j) {
                float r = fmaxf(fmaf(w1j[j], v, b1j[j]), 0.f);
                acc = fmaf(w2s[j], r, acc);
            }
            float r2 = fmaxf(acc, 0.f);
            t2s += r2;
            t2s2 = fmaf(r2, r2, t2s2);
            pp[u] = f2bf(r2);
        }
        *(ushort4*)(op + i0) = pk;   // 8 B store, aligned
    }

    __syncthreads();                 // phase-A reads of redA/redB done
    redA[slice][lane] = t2s;
    redB[slice][lane] = t2s2;
    __syncthreads();
    if (threadIdx.x < 32) {
        float S = 0.f, S2 = 0.f;
        #pragma unroll
        for (int k = 0; k < 8; ++k) { S += redA[k][threadIdx.x]; S2 += redB[k][threadIdx.x]; }
        float m = S * (1.f / 256.f);
        float v = fmaf(-m, m, S2 * (1.f / 256.f));
        const int cw = (cb << 5) + threadIdx.x;
        m2g[cw]   = m;
        inv2g[cw] = rsqrtf(v + EPS);
    }
}

// ---------------------------------------------------------------------------
// Kernel 2: XCD-local layer-3 partial gather-dot.
// Grid = NTF*8 blocks: t = bid>>3, x = bid&7.  With round-robin dispatch,
// x == this block's XCD, and block (t,x) reads ONLY gene slice
// [1024x, 1024x+1024) = a 2.1 MB contiguous range of h2 that fits (and
// stays) in XCD x's 4 MiB L2.  ~117 of the 134 MB gather becomes L2 hits.
// Each TF has ~8 of its 64 genes per slice (binomial).  BN2 is folded into
// the weights; the per-slice bias correction (sum w~*m2) is subtracted here.
// Partials go to part[x][t][r] f32; kernel 3 combines + BN3.
// ---------------------------------------------------------------------------
__global__ __launch_bounds__(256) void gather3(
    const unsigned short* __restrict__ h2,  // [HID][B] bf16 bits
    const float* __restrict__ m2g,          // [HID]
    const float* __restrict__ inv2g,        // [HID]
    const float* __restrict__ w3,           // [NTF*256]
    const int*   __restrict__ cols3,        // [NTF*256]
    float* __restrict__ part)               // [8][NTF][256]
{
    const int t   = blockIdx.x >> 3;
    const int x   = blockIdx.x & 7;
    const int tid = threadIdx.x;

    __shared__ int   gl[72];       // matched genes (padded to mult of 8)
    __shared__ float wls[288];     // BN2-folded weights, 4 per gene
    __shared__ float accq[4][256];
    __shared__ int   nS;
    __shared__ float bpS;

    // wave 0: scan the TF's 64 genes, compact the ones in slice x
    if (tid < 64) {
        const int  g     = cols3[(t << 8) + (tid << 2)] >> 2;
        const bool match = (g >> 10) == x;
        const unsigned long long mask = __ballot(match);
        const int  pos = __popcll(mask & ((1ull << tid) - 1ull));
        const int  n   = __popcll(mask);
        float bpv = 0.f;
        if (match) {
            gl[pos] = g;
            #pragma unroll
            for (int j = 0; j < 4; ++j) {
                float wv = w3[(t << 8) + (tid << 2) + j] * inv2g[(g << 2) + j];
                wls[(pos << 2) + j] = wv;
                bpv = fmaf(wv, m2g[(g << 2) + j], bpv);
            }
        }
        #pragma unroll
        for (int o = 32; o > 0; o >>= 1) bpv += __shfl_xor(bpv, o);
        // pad to multiple of 8 with zero-weight entries (keeps load batches of 8)
        const int nP = (n + 7) & ~7;
        for (int idx = n + tid; idx < nP; idx += 64) {
            gl[idx] = 0;
            #pragma unroll
            for (int j = 0; j < 4; ++j) wls[(idx << 2) + j] = 0.f;
        }
        if (tid == 0) { nS = nP; bpS = bpv; }
    }
    __syncthreads();

    // gather-dot: thread -> (col j = tid>>6, rows 4*(tid&63)..+3)
    const int   n   = nS;
    const int   j   = tid >> 6;
    const char* h2c = (const char*)h2 + (j << 9) + ((tid & 63) << 3);
    float a0 = 0.f, a1 = 0.f, a2 = 0.f, a3 = 0.f;
    for (int k0 = 0; k0 < n; k0 += 8) {
        #pragma unroll
        for (int u = 0; u < 8; ++u) {           // 8 independent loads in flight
            const int   k = k0 + u;
            const int   g = gl[k];
            const float w = wls[(k << 2) + j];
            const uint2 v = *(const uint2*)(h2c + ((size_t)g << 11));
            union { unsigned b; float f; } p0, p1, p2, p3;
            p0.b = v.x << 16; p1.b = v.x & 0xffff0000u;
            p2.b = v.y << 16; p3.b = v.y & 0xffff0000u;
            a0 = fmaf(w, p0.f, a0); a1 = fmaf(w, p1.f, a1);
            a2 = fmaf(w, p2.f, a2); a3 = fmaf(w, p3.f, a3);
        }
    }
    *(float4*)&accq[j][(tid & 63) << 2] = make_float4(a0, a1, a2, a3);
    __syncthreads();

    // tid = batch row now; combine 4 col-groups, subtract bias partial
    const float p = accq[0][tid] + accq[1][tid] + accq[2][tid] + accq[3][tid] - bpS;
    part[(((x << 10) + t) << 8) + tid] = p;
}

// ---------------------------------------------------------------------------
// Kernel 3: combine 8 slice-partials + BN3 + transposed output store.
// ---------------------------------------------------------------------------
__global__ __launch_bounds__(256) void bn3(
    const float* __restrict__ part,   // [8][NTF][256]
    const float* __restrict__ b3,     // [NTF]
    float* __restrict__ out)          // [B][NTF]
{
    const int t   = blockIdx.x;
    const int tid = threadIdx.x;
    __shared__ float rs[4], rs2[4];

    float z = b3[t];
    #pragma unroll
    for (int xx = 0; xx < 8; ++xx)
        z += part[(((xx << 10) + t) << 8) + tid];

    float s = z, s2 = z * z;
    #pragma unroll
    for (int o = 32; o > 0; o >>= 1) {
        s  += __shfl_xor(s, o);
        s2 += __shfl_xor(s2, o);
    }
    if ((tid & 63) == 0) { rs[tid >> 6] = s; rs2[tid >> 6] = s2; }
    __syncthreads();
    float S  = rs[0] + rs[1] + rs[2] + rs[3];
    float S2 = rs2[0] + rs2[1] + rs2[2] + rs2[3];
    float m  = S * (1.f / 256.f);
    float v  = fmaf(-m, m, S2 * (1.f / 256.f));
    float invs = rsqrtf(v + EPS);
    out[(size_t)tid * NTF + t] = (z - m) * invs;
}

// ---------------------------------------------------------------------------
extern "C" void kernel_launch(void* const* d_in, const int* in_sizes, int n_in,
                              void* d_out, int out_size, void* d_ws, size_t ws_size,
                              hipStream_t stream) {
    const float* x   = (const float*)d_in[0];
    const float* w1  = (const float*)d_in[1];
    const float* b1  = (const float*)d_in[2];
    const float* w2  = (const float*)d_in[3];
    const float* b2  = (const float*)d_in[4];
    const float* w3  = (const float*)d_in[5];
    const float* b3  = (const float*)d_in[6];
    const int* cols3 = (const int*)d_in[12];
    float* out = (float*)d_out;

    // ws: h2 [HID][B] bf16 (16.8 MB) + m2 [HID] + inv2 [HID] f32 + part 8.4 MB
    unsigned short* h2 = (unsigned short*)d_ws;
    float* m2g   = (float*)(h2 + (size_t)HID * B);
    float* inv2g = m2g + HID;
    float* part  = inv2g + HID;

    fused12<<<HID / 32, 256, 0, stream>>>(x, w1, b1, w2, b2, h2, m2g, inv2g);
    gather3<<<NTF * 8, 256, 0, stream>>>(h2, m2g, inv2g, w3, cols3, part);
    bn3<<<NTF, 256, 0, stream>>>(part, b3, out);
}